// Round 9
// baseline (461.763 us; speedup 1.0000x reference)
//
#include <hip/hip_runtime.h>

// Problem constants
#define NN 100000      // nodes
#define NE 600000      // edges
#define D  128         // feature dim in (both layers)
#define DOUT2 96
#define NREL 4
#define KREL 512       // NREL * D
#define KCAT 640       // KREL + D
#define SCAN_B 98      // ceil(NN / 1024)

typedef short short8 __attribute__((ext_vector_type(8)));   // 8 bf16
typedef float f32x4  __attribute__((ext_vector_type(4)));

// fp32 -> bf16 round-to-nearest-even (finite inputs)
__device__ __forceinline__ ushort f2bf(float x) {
    unsigned u = __builtin_bit_cast(unsigned, x);
    u += 0x7fffu + ((u >> 16) & 1u);
    return (ushort)(u >> 16);
}
__device__ __forceinline__ float bfhi(unsigned u) {
    return __builtin_bit_cast(float, u & 0xffff0000u);
}
__device__ __forceinline__ float bflo(unsigned u) {
    return __builtin_bit_cast(float, u << 16);
}

// ---------------------------------------------------------------------------
// Fused independent prep: zero cnt, zero fill, x->bf16, pack Wcp1, pack Wcp2.
__global__ void prep0(const float* __restrict__ x, ushort* __restrict__ Xb,
                      const float* __restrict__ W1, const float* __restrict__ root1,
                      short* __restrict__ Wp1,
                      const float* __restrict__ W2, const float* __restrict__ root2,
                      short* __restrict__ Wp2,
                      float* __restrict__ cnt, int* __restrict__ fill) {
    int i = blockIdx.x * 256 + threadIdx.x;
    const int S0 = (NN * NREL) / 4;   // 100000 float4 zeros of cnt
    const int S1 = NN / 4;            // 25000 int4 zeros of fill
    const int S2 = (NN * D) / 4;      // 3200000 float4->ushort4 converts
    const int S3 = KCAT * D;          // 81920 pack1 elements
    const int S4 = KCAT * DOUT2;      // 61440 pack2 elements
    if (i < S0) { ((float4*)cnt)[i] = make_float4(0.f, 0.f, 0.f, 0.f); return; }
    i -= S0;
    if (i < S1) { ((int4*)fill)[i] = make_int4(0, 0, 0, 0); return; }
    i -= S1;
    if (i < S2) {
        float4 v = ((const float4*)x)[i];
        ushort4 o;
        o.x = f2bf(v.x); o.y = f2bf(v.y); o.z = f2bf(v.z); o.w = f2bf(v.w);
        ((ushort4*)Xb)[i] = o;
        return;
    }
    i -= S2;
    if (i < S3) {   // Wcp[kq][n][j] = Wcat[kq*8+j][n], BN = 128
        int j = i & 7, rest = i >> 3;
        int n = rest % D, kq = rest / D;
        int k = kq * 8 + j;
        float v = (k < KREL) ? W1[(size_t)k * D + n] : root1[(size_t)(k - KREL) * D + n];
        Wp1[i] = (short)f2bf(v);
        return;
    }
    i -= S3;
    if (i < S4) {   // BN = 96
        int j = i & 7, rest = i >> 3;
        int n = rest % DOUT2, kq = rest / DOUT2;
        int k = kq * 8 + j;
        float v = (k < KREL) ? W2[(size_t)k * DOUT2 + n] : root2[(size_t)(k - KREL) * DOUT2 + n];
        Wp2[i] = (short)f2bf(v);
        return;
    }
}

// ---------------------------------------------------------------------------
// cnt[v][r] = #edges with dst=v, etype=r
__global__ void count_deg(const int* __restrict__ dst,
                          const int* __restrict__ et,
                          float* __restrict__ cnt) {
    int e = blockIdx.x * blockDim.x + threadIdx.x;
    if (e < NE) unsafeAtomicAdd(&cnt[dst[e] * NREL + et[e]], 1.0f);
}

// ---------------------------------------------------------------------------
// Prefix sum of per-node degree -> off[0..NN] (3-kernel scan)
__global__ void scan1(const float* __restrict__ cnt, int* __restrict__ bsum) {
    __shared__ int s[256];
    int tid = threadIdx.x;
    int base = blockIdx.x * 1024 + tid * 4;
    int t = 0;
    for (int i = 0; i < 4; i++) {
        int v = base + i;
        if (v < NN) {
            float4 c = *(const float4*)&cnt[(size_t)v * 4];
            t += (int)(c.x + c.y + c.z + c.w);
        }
    }
    s[tid] = t; __syncthreads();
    for (int o = 128; o > 0; o >>= 1) {
        if (tid < o) s[tid] += s[tid + o];
        __syncthreads();
    }
    if (tid == 0) bsum[blockIdx.x] = s[0];
}

__global__ void scan2(int* __restrict__ bsum) {  // 1 block of 128; exclusive in-place
    __shared__ int s[128];
    int tid = threadIdx.x;
    int mine = (tid < SCAN_B) ? bsum[tid] : 0;
    s[tid] = mine; __syncthreads();
    for (int o = 1; o < 128; o <<= 1) {
        int v = (tid >= o) ? s[tid - o] : 0;
        __syncthreads();
        s[tid] += v;
        __syncthreads();
    }
    if (tid < SCAN_B) bsum[tid] = s[tid] - mine;
}

__global__ void scan3(const float* __restrict__ cnt, const int* __restrict__ bsum,
                      int* __restrict__ off) {
    __shared__ int s[256];
    int tid = threadIdx.x;
    int base = blockIdx.x * 1024 + tid * 4;
    int d[4]; int t = 0;
    for (int i = 0; i < 4; i++) {
        int v = base + i; d[i] = 0;
        if (v < NN) {
            float4 c = *(const float4*)&cnt[(size_t)v * 4];
            d[i] = (int)(c.x + c.y + c.z + c.w);
        }
        t += d[i];
    }
    int mine = t;
    s[tid] = t; __syncthreads();
    for (int o = 1; o < 256; o <<= 1) {
        int v = (tid >= o) ? s[tid - o] : 0;
        __syncthreads();
        s[tid] += v;
        __syncthreads();
    }
    int ex = s[tid] - mine + bsum[blockIdx.x];
    for (int i = 0; i < 4; i++) {
        int v = base + i;
        if (v < NN) { off[v] = ex; ex += d[i]; }
    }
    if (blockIdx.x == 0 && tid == 0) off[NN] = NE;
}

// ---------------------------------------------------------------------------
// Bucket edges by dst; packed (src<<2)|etype
__global__ void bucket_edges(const int* __restrict__ src, const int* __restrict__ dst,
                             const int* __restrict__ et, const int* __restrict__ off,
                             int* __restrict__ fill, int* __restrict__ srcpk) {
    int e = blockIdx.x * blockDim.x + threadIdx.x;
    if (e >= NE) return;
    int dn = dst[e];
    int pos = off[dn] + atomicAdd(&fill[dn], 1);
    srcpk[pos] = (src[e] << 2) | et[e];
}

// ---------------------------------------------------------------------------
// Fused RGCN layer — 16-node block, max-occupancy variant.
// Block = 256 threads (4 waves), 16 dst nodes, one 16 KB LDS tile
// [kq16=64][node=16][8 bf16], node slot XOR-swizzled by kq&7 (measured on
// the 32-node version: SQ_LDS_BANK_CONFLICT 5.6M -> 0; register-free).
// RATIONALE (R8 post-mortem): kernel is latency-bound — VALUBusy 36%,
// MfmaUtil 7.5%, HBM 18%, Occupancy 36% (~11.6/32 waves). All per-wave ILP
// levers (8-wide batch, f32x2 pack) spilled at the 48-64 VGPR allocation
// and regressed. This variant halves LDS so residency doubles:
// __launch_bounds__(256,8) caps VGPR at exactly 64 (proven body compiles
// 48-64) and 16 KB LDS allows 8 blocks/CU = 32 waves = 100% occupancy.
// Spill tripwire: WRITE_SIZE must stay == output size (25000 KiB layer 1).
//   Phase 1: 16 quarter-wave chains, ONE node each; 4-wide unrolled gather
//            batches (R5 body, proven no-spill). fp32 acc, predicated
//            per-relation scales.
//   Root MFMAs (global-only operands) run BEFORE the barrier.
//   Phase 2: 16 x BN from 640 k. Wave w owns col-frags {w, 4+w}; for
//            BN=96 the second frag is skipped by a wave-uniform branch.
template <int BN, bool RELU, bool OUT_BF16>
__global__ __launch_bounds__(256, 8) void rgcn_fused(
    const ushort* __restrict__ Xb,   // [M,128] bf16
    const int*   __restrict__ srcpk, // [NE] bucketed, (src<<2)|t
    const int*   __restrict__ off,   // [M+1]
    const float* __restrict__ cnt,   // [M,4]
    const short* __restrict__ Wcp,   // [80][BN][8] bf16
    const float* __restrict__ bias,  // [BN]
    void*        __restrict__ Cout,  // [M,BN] bf16 or f32
    int M) {
    __shared__ short At[64 * 16 * 8];        // 16 KB

    const int tid  = threadIdx.x;
    const int wave = tid >> 6;
    const int lane = tid & 63;
    const int l    = lane & 15;     // phase1: feat group / phase2: m16 (col)
    const int qw   = lane >> 4;     // phase1: quarter / phase2: k-quad q
    const int g    = wave * 4 + qw; // chain id 0..15 == node index in tile
    const int v0   = blockIdx.x * 16;

    // ---- phase 1: one node per chain ----
    {
        int v = v0 + g;             // NN % 16 == 0 -> always < M
        float acc[4][8];
#pragma unroll
        for (int r = 0; r < 4; r++)
#pragma unroll
            for (int j = 0; j < 8; j++) acc[r][j] = 0.0f;

        float4 c4 = *(const float4*)&cnt[(size_t)v * 4];
        float nrm0 = 1.0f / fmaxf(c4.x, 1.0f);
        float nrm1 = 1.0f / fmaxf(c4.y, 1.0f);
        float nrm2 = 1.0f / fmaxf(c4.z, 1.0f);
        float nrm3 = 1.0f / fmaxf(c4.w, 1.0f);
        int e = off[v], end = off[v + 1];

#define EDGE_ACC(PK, XB) {                                                  \
        int t_ = (PK) & 3;                                                  \
        float s0 = (t_ == 0) ? nrm0 : 0.0f;                                 \
        float s1 = (t_ == 1) ? nrm1 : 0.0f;                                 \
        float s2 = (t_ == 2) ? nrm2 : 0.0f;                                 \
        float s3 = (t_ == 3) ? nrm3 : 0.0f;                                 \
        float xf[8];                                                        \
        xf[0] = bflo(XB.x); xf[1] = bfhi(XB.x);                             \
        xf[2] = bflo(XB.y); xf[3] = bfhi(XB.y);                             \
        xf[4] = bflo(XB.z); xf[5] = bfhi(XB.z);                             \
        xf[6] = bflo(XB.w); xf[7] = bfhi(XB.w);                             \
        _Pragma("unroll")                                                   \
        for (int j = 0; j < 8; j++) {                                       \
            acc[0][j] += s0 * xf[j];                                        \
            acc[1][j] += s1 * xf[j];                                        \
            acc[2][j] += s2 * xf[j];                                        \
            acc[3][j] += s3 * xf[j];                                        \
        } }

        for (; e + 3 < end; e += 4) {   // 4 gathers in flight per chain
            int p0 = srcpk[e],     p1 = srcpk[e + 1];
            int p2 = srcpk[e + 2], p3 = srcpk[e + 3];
            uint4 x0 = *(const uint4*)&Xb[(size_t)(p0 >> 2) * D + l * 8];
            uint4 x1 = *(const uint4*)&Xb[(size_t)(p1 >> 2) * D + l * 8];
            uint4 x2 = *(const uint4*)&Xb[(size_t)(p2 >> 2) * D + l * 8];
            uint4 x3 = *(const uint4*)&Xb[(size_t)(p3 >> 2) * D + l * 8];
            EDGE_ACC(p0, x0); EDGE_ACC(p1, x1);
            EDGE_ACC(p2, x2); EDGE_ACC(p3, x3);
        }
        for (; e < end; e++) {
            int p0 = srcpk[e];
            uint4 x0 = *(const uint4*)&Xb[(size_t)(p0 >> 2) * D + l * 8];
            EDGE_ACC(p0, x0);
        }
#undef EDGE_ACC

        // stage to LDS in A-frag order: kq16 = r*16 + l, node slot XOR-swizzled
        // by kq&7 -> ds_write_b128 spreads over banks (measured 0 conflicts)
#pragma unroll
        for (int r = 0; r < 4; r++) {
            short8 w;
#pragma unroll
            for (int j = 0; j < 8; j++) w[j] = (short)f2bf(acc[r][j]);
            int kq = r * 16 + l;
            *(short8*)&At[(kq * 16 + (g ^ (kq & 7))) * 8] = w;
        }
    }

    // ---- phase 2 setup: wave w owns col-frags nb0 = w*16 and nb1 = 64+w*16
    const int m16  = l;
    const int q    = qw;
    const int nb0  = wave * 16;
    const int nb1  = 64 + wave * 16;
    const bool has1 = (nb1 < BN);   // wave-uniform; false for waves 2,3 @ BN=96
    f32x4 a0 = (f32x4)0.0f, a1 = (f32x4)0.0f;

    // root part first (k = 512..639, global-only operands): phase-1 registers
    // are dead here; fast waves do these MFMAs while slow chains gather.
    {
        int rowc = v0 + m16;
        const ushort* Xrow = Xb + (size_t)rowc * D;
#pragma unroll
        for (int s2 = 0; s2 < 4; s2++) {
            short8 af = *(const short8*)&Xrow[s2 * 32 + q * 8];
            size_t kqb = (size_t)((16 + s2) * 4 + q) * BN;
            a0 = __builtin_amdgcn_mfma_f32_16x16x32_bf16(
                af, *(const short8*)(Wcp + (kqb + nb0 + m16) * 8), a0, 0, 0, 0);
            if (has1)
                a1 = __builtin_amdgcn_mfma_f32_16x16x32_bf16(
                    af, *(const short8*)(Wcp + (kqb + nb1 + m16) * 8), a1, 0, 0, 0);
        }
    }

    __syncthreads();

    // ---- phase 2: 16x512 @ 512xBN from LDS ----
#pragma unroll 4
    for (int ks = 0; ks < 16; ks++) {
        int kq = ks * 4 + q;
        short8 af = *(const short8*)&At[(kq * 16 + (m16 ^ (kq & 7))) * 8];
        size_t kqb = (size_t)kq * BN;
        a0 = __builtin_amdgcn_mfma_f32_16x16x32_bf16(
            af, *(const short8*)(Wcp + (kqb + nb0 + m16) * 8), a0, 0, 0, 0);
        if (has1)
            a1 = __builtin_amdgcn_mfma_f32_16x16x32_bf16(
                af, *(const short8*)(Wcp + (kqb + nb1 + m16) * 8), a1, 0, 0, 0);
    }

    // ---- epilogue ----
    {
        int n = nb0 + m16;
        float b = bias[n];
#pragma unroll
        for (int r = 0; r < 4; r++) {
            int m = v0 + q * 4 + r;
            float vv = a0[r] + b;
            if (RELU) vv = fmaxf(vv, 0.0f);
            if (OUT_BF16) ((ushort*)Cout)[(size_t)m * BN + n] = f2bf(vv);
            else          ((float*)Cout)[(size_t)m * BN + n]  = vv;
        }
    }
    if (has1) {
        int n = nb1 + m16;
        float b = bias[n];
#pragma unroll
        for (int r = 0; r < 4; r++) {
            int m = v0 + q * 4 + r;
            float vv = a1[r] + b;
            if (RELU) vv = fmaxf(vv, 0.0f);
            if (OUT_BF16) ((ushort*)Cout)[(size_t)m * BN + n] = f2bf(vv);
            else          ((float*)Cout)[(size_t)m * BN + n]  = vv;
        }
    }
}

// ---------------------------------------------------------------------------
extern "C" void kernel_launch(void* const* d_in, const int* in_sizes, int n_in,
                              void* d_out, int out_size, void* d_ws, size_t ws_size,
                              hipStream_t stream) {
    const float* x     = (const float*)d_in[0];
    const int*   ei    = (const int*)d_in[1];
    const int*   et    = (const int*)d_in[2];
    const float* W1    = (const float*)d_in[3];
    const float* root1 = (const float*)d_in[4];
    const float* b1    = (const float*)d_in[5];
    const float* W2    = (const float*)d_in[6];
    const float* root2 = (const float*)d_in[7];
    const float* b2    = (const float*)d_in[8];
    const int* srcp = ei;
    const int* dstp = ei + NE;
    float* out = (float*)d_out;

    // Workspace layout (all segments 16-B aligned)
    short*  Wp1  = (short*)d_ws;                          // 640*128 bf16
    short*  Wp2  = Wp1 + (size_t)KCAT * D;                // 640*96  bf16
    ushort* Xb   = (ushort*)(Wp2 + (size_t)KCAT * DOUT2); // NN*128 bf16
    ushort* h    = Xb + (size_t)NN * D;                   // NN*128 bf16
    float*  cnt  = (float*)(h + (size_t)NN * D);          // NN*4 f32
    int*    off  = (int*)(cnt + (size_t)NN * NREL);       // NN+1
    int*    fill = off + (NN + 1);                        // NN
    int*    bsum = fill + NN;                             // 128
    int*    srcpk= bsum + 128;                            // NE

    // ---- prep (shared by both layers) ----
    {
        const int S = (NN * NREL) / 4 + NN / 4 + (NN * D) / 4 + KCAT * D + KCAT * DOUT2;
        prep0<<<(S + 255) / 256, 256, 0, stream>>>(x, Xb, W1, root1, Wp1,
                                                   W2, root2, Wp2, cnt, fill);
    }
    count_deg<<<(NE + 255) / 256, 256, 0, stream>>>(dstp, et, cnt);
    scan1<<<SCAN_B, 256, 0, stream>>>(cnt, bsum);
    scan2<<<1, 128, 0, stream>>>(bsum);
    scan3<<<SCAN_B, 256, 0, stream>>>(cnt, bsum, off);
    bucket_edges<<<(NE + 255) / 256, 256, 0, stream>>>(srcp, dstp, et, off, fill, srcpk);

    const int fblocks = NN / 16;  // 6250 (exact)

    // ---- Layer 1: h = relu(agg(x) @ W1cat + b1), bf16 out ----
    rgcn_fused<128, true, true><<<fblocks, 256, 0, stream>>>(
        Xb, srcpk, off, cnt, Wp1, b1, h, NN);
    // ---- Layer 2: out = agg(h) @ W2cat + b2, f32 out ----
    rgcn_fused<96, false, false><<<fblocks, 256, 0, stream>>>(
        h, srcpk, off, cnt, Wp2, b2, out, NN);
}

// Round 10
// 366.823 us; speedup vs baseline: 1.2588x; 1.2588x over previous
//
#include <hip/hip_runtime.h>

// Problem constants
#define NN 100000      // nodes
#define NE 600000      // edges
#define D  128         // feature dim in (both layers)
#define DOUT2 96
#define NREL 4
#define KREL 512       // NREL * D
#define KCAT 640       // KREL + D
#define SCAN_B 98      // ceil(NN / 1024)

typedef short short8 __attribute__((ext_vector_type(8)));   // 8 bf16
typedef float f32x4  __attribute__((ext_vector_type(4)));

// fp32 -> bf16 round-to-nearest-even (finite inputs)
__device__ __forceinline__ ushort f2bf(float x) {
    unsigned u = __builtin_bit_cast(unsigned, x);
    u += 0x7fffu + ((u >> 16) & 1u);
    return (ushort)(u >> 16);
}
__device__ __forceinline__ float bfhi(unsigned u) {
    return __builtin_bit_cast(float, u & 0xffff0000u);
}
__device__ __forceinline__ float bflo(unsigned u) {
    return __builtin_bit_cast(float, u << 16);
}

// ---------------------------------------------------------------------------
// Fused independent prep: zero cnt, zero fill (NN*4), x->bf16, pack Wcp1/2.
__global__ void prep0(const float* __restrict__ x, ushort* __restrict__ Xb,
                      const float* __restrict__ W1, const float* __restrict__ root1,
                      short* __restrict__ Wp1,
                      const float* __restrict__ W2, const float* __restrict__ root2,
                      short* __restrict__ Wp2,
                      float* __restrict__ cnt, int* __restrict__ fill) {
    int i = blockIdx.x * 256 + threadIdx.x;
    const int S0 = (NN * NREL) / 4;   // 100000 float4 zeros of cnt
    const int S1 = NN;                // 100000 int4 zeros of fill[NN*4]
    const int S2 = (NN * D) / 4;      // 3200000 float4->ushort4 converts
    const int S3 = KCAT * D;          // 81920 pack1 elements
    const int S4 = KCAT * DOUT2;      // 61440 pack2 elements
    if (i < S0) { ((float4*)cnt)[i] = make_float4(0.f, 0.f, 0.f, 0.f); return; }
    i -= S0;
    if (i < S1) { ((int4*)fill)[i] = make_int4(0, 0, 0, 0); return; }
    i -= S1;
    if (i < S2) {
        float4 v = ((const float4*)x)[i];
        ushort4 o;
        o.x = f2bf(v.x); o.y = f2bf(v.y); o.z = f2bf(v.z); o.w = f2bf(v.w);
        ((ushort4*)Xb)[i] = o;
        return;
    }
    i -= S2;
    if (i < S3) {   // Wcp[kq][n][j] = Wcat[kq*8+j][n], BN = 128
        int j = i & 7, rest = i >> 3;
        int n = rest % D, kq = rest / D;
        int k = kq * 8 + j;
        float v = (k < KREL) ? W1[(size_t)k * D + n] : root1[(size_t)(k - KREL) * D + n];
        Wp1[i] = (short)f2bf(v);
        return;
    }
    i -= S3;
    if (i < S4) {   // BN = 96
        int j = i & 7, rest = i >> 3;
        int n = rest % DOUT2, kq = rest / DOUT2;
        int k = kq * 8 + j;
        float v = (k < KREL) ? W2[(size_t)k * DOUT2 + n] : root2[(size_t)(k - KREL) * DOUT2 + n];
        Wp2[i] = (short)f2bf(v);
        return;
    }
}

// ---------------------------------------------------------------------------
// cnt[v][r] = #edges with dst=v, etype=r
__global__ void count_deg(const int* __restrict__ dst,
                          const int* __restrict__ et,
                          float* __restrict__ cnt) {
    int e = blockIdx.x * blockDim.x + threadIdx.x;
    if (e < NE) unsafeAtomicAdd(&cnt[dst[e] * NREL + et[e]], 1.0f);
}

// ---------------------------------------------------------------------------
// Prefix sum of per-node degree -> off[0..NN] (3-kernel scan)
__global__ void scan1(const float* __restrict__ cnt, int* __restrict__ bsum) {
    __shared__ int s[256];
    int tid = threadIdx.x;
    int base = blockIdx.x * 1024 + tid * 4;
    int t = 0;
    for (int i = 0; i < 4; i++) {
        int v = base + i;
        if (v < NN) {
            float4 c = *(const float4*)&cnt[(size_t)v * 4];
            t += (int)(c.x + c.y + c.z + c.w);
        }
    }
    s[tid] = t; __syncthreads();
    for (int o = 128; o > 0; o >>= 1) {
        if (tid < o) s[tid] += s[tid + o];
        __syncthreads();
    }
    if (tid == 0) bsum[blockIdx.x] = s[0];
}

__global__ void scan2(int* __restrict__ bsum) {  // 1 block of 128; exclusive in-place
    __shared__ int s[128];
    int tid = threadIdx.x;
    int mine = (tid < SCAN_B) ? bsum[tid] : 0;
    s[tid] = mine; __syncthreads();
    for (int o = 1; o < 128; o <<= 1) {
        int v = (tid >= o) ? s[tid - o] : 0;
        __syncthreads();
        s[tid] += v;
        __syncthreads();
    }
    if (tid < SCAN_B) bsum[tid] = s[tid] - mine;
}

__global__ void scan3(const float* __restrict__ cnt, const int* __restrict__ bsum,
                      int* __restrict__ off) {
    __shared__ int s[256];
    int tid = threadIdx.x;
    int base = blockIdx.x * 1024 + tid * 4;
    int d[4]; int t = 0;
    for (int i = 0; i < 4; i++) {
        int v = base + i; d[i] = 0;
        if (v < NN) {
            float4 c = *(const float4*)&cnt[(size_t)v * 4];
            d[i] = (int)(c.x + c.y + c.z + c.w);
        }
        t += d[i];
    }
    int mine = t;
    s[tid] = t; __syncthreads();
    for (int o = 1; o < 256; o <<= 1) {
        int v = (tid >= o) ? s[tid - o] : 0;
        __syncthreads();
        s[tid] += v;
        __syncthreads();
    }
    int ex = s[tid] - mine + bsum[blockIdx.x];
    for (int i = 0; i < 4; i++) {
        int v = base + i;
        if (v < NN) { off[v] = ex; ex += d[i]; }
    }
    if (blockIdx.x == 0 && tid == 0) off[NN] = NE;
}

// ---------------------------------------------------------------------------
// Bucket edges by (dst, etype): within a node's range, edges are grouped by
// relation (segment r base = off[dn] + prefix of cnt[dn][<r]). This lets the
// fused kernel use ONE 8-reg accumulator per segment and apply the norm once
// at segment end instead of per-edge predicated scales.
__global__ void bucket_edges(const int* __restrict__ src, const int* __restrict__ dst,
                             const int* __restrict__ et, const int* __restrict__ off,
                             int* __restrict__ fill, int* __restrict__ srcpk,
                             const float* __restrict__ cnt) {
    int e = blockIdx.x * blockDim.x + threadIdx.x;
    if (e >= NE) return;
    int dn = dst[e];
    int t  = et[e];
    float4 c4 = *(const float4*)&cnt[(size_t)dn * 4];
    int base = off[dn];
    if (t > 0) base += (int)c4.x;
    if (t > 1) base += (int)c4.y;
    if (t > 2) base += (int)c4.z;
    int pos = base + atomicAdd(&fill[dn * 4 + t], 1);
    srcpk[pos] = src[e];
}

// ---------------------------------------------------------------------------
// Fused RGCN layer — relation-segmented aggregation (R10).
// Block = 256 threads (4 waves), 32 dst nodes, one 32 KB LDS tile
// [kq16=64][node=32][8 bf16], node slot XOR-swizzled by kq&7 (measured:
// SQ_LDS_BANK_CONFLICT 5.6M -> 0).
// R9 lesson: occupancy can't rise while phase 1 pins 32 acc VGPRs —
// (256,8) forced 32-VGPR alloc and spilled 294 MB. R10 shrinks the
// accumulator itself: edges are relation-sorted per node, so phase 1 runs
// 4 sequential segments with ONE acc[8] (8 VGPRs), plain adds per edge
// (no etype unpack, no predicated scales — per-edge VALU ~53 -> ~22 ops),
// and applies 1/max(cnt_r,1) once at segment end, writing that relation's
// short8 straight to LDS. Peak live set ~40 VGPR.
// Spill tripwire: WRITE_SIZE must stay == output size (25000 KiB layer 1).
//   Root MFMAs (global-only operands) run BEFORE the barrier.
//   Phase 2 (after one barrier): wave w computes quadrant
//            (m-half = w&1, n-half = w>>1): 16 nodes x NFW*16 cols.
template <int BN, bool RELU, bool OUT_BF16>
__global__ __launch_bounds__(256, 5) void rgcn_fused(
    const ushort* __restrict__ Xb,   // [M,128] bf16
    const int*   __restrict__ srcpk, // [NE] bucketed by (dst, etype); raw src
    const int*   __restrict__ off,   // [M+1]
    const float* __restrict__ cnt,   // [M,4]
    const short* __restrict__ Wcp,   // [80][BN][8] bf16
    const float* __restrict__ bias,  // [BN]
    void*        __restrict__ Cout,  // [M,BN] bf16 or f32
    int M) {
    constexpr int NFW = (BN / 16 + 1) / 2;   // frags per wave: 4 (BN=128) / 3 (BN=96)
    __shared__ short At[64 * 32 * 8];        // 32 KB

    const int tid  = threadIdx.x;
    const int wave = tid >> 6;
    const int lane = tid & 63;
    const int l    = lane & 15;     // phase1: feat group / phase2: m16
    const int qw   = lane >> 4;     // phase1: quarter / phase2: k-quad q
    const int g    = wave * 4 + qw; // chain id 0..15
    const int v0   = blockIdx.x * 32;

    // ---- phase 1: aggregate 32 nodes (2 per chain), 4 relation segments ----
#pragma unroll
    for (int half = 0; half < 2; half++) {
        int nv = g + half * 16;
        int v  = v0 + nv;           // NN % 32 == 0 -> always < M

        float4 c4 = *(const float4*)&cnt[(size_t)v * 4];
        int e = off[v];

#define ACC8(XB) {                                                          \
        acc[0] += bflo(XB.x); acc[1] += bfhi(XB.x);                         \
        acc[2] += bflo(XB.y); acc[3] += bfhi(XB.y);                         \
        acc[4] += bflo(XB.z); acc[5] += bfhi(XB.z);                         \
        acc[6] += bflo(XB.w); acc[7] += bfhi(XB.w); }

#pragma unroll
        for (int r = 0; r < 4; r++) {
            float cf = (r == 0) ? c4.x : (r == 1) ? c4.y : (r == 2) ? c4.z : c4.w;
            int cr  = (int)cf;
            int end = e + cr;
            float acc[8];
#pragma unroll
            for (int j = 0; j < 8; j++) acc[j] = 0.0f;

            for (; e + 3 < end; e += 4) {   // 4 gathers in flight per chain
                int p0 = srcpk[e],     p1 = srcpk[e + 1];
                int p2 = srcpk[e + 2], p3 = srcpk[e + 3];
                uint4 x0 = *(const uint4*)&Xb[(size_t)p0 * D + l * 8];
                uint4 x1 = *(const uint4*)&Xb[(size_t)p1 * D + l * 8];
                uint4 x2 = *(const uint4*)&Xb[(size_t)p2 * D + l * 8];
                uint4 x3 = *(const uint4*)&Xb[(size_t)p3 * D + l * 8];
                ACC8(x0); ACC8(x1); ACC8(x2); ACC8(x3);
            }
            for (; e < end; e++) {
                int p0 = srcpk[e];
                uint4 x0 = *(const uint4*)&Xb[(size_t)p0 * D + l * 8];
                ACC8(x0);
            }

            // segment epilogue: scale once, stage to LDS (A-frag order,
            // kq16 = r*16 + l, node slot XOR-swizzled by kq&7)
            float nrm = 1.0f / fmaxf(cf, 1.0f);
            short8 w;
#pragma unroll
            for (int j = 0; j < 8; j++) w[j] = (short)f2bf(acc[j] * nrm);
            int kq = r * 16 + l;
            *(short8*)&At[(kq * 32 + (nv ^ (kq & 7))) * 8] = w;
        }
#undef ACC8
    }

    // ---- phase 2 setup ----
    const int m16   = l;
    const int q     = qw;
    const int mt    = wave & 1;           // m-half (16 nodes)
    const int nbase = (wave >> 1) * NFW * 16;   // n-offset
    f32x4 acc2[NFW];
#pragma unroll
    for (int i = 0; i < NFW; i++) acc2[i] = (f32x4)0.0f;

    // root part first (k = 512..639, global-only operands): phase-1 registers
    // are dead here; fast waves do these MFMAs while slow chains gather.
    {
        int rowc = v0 + mt * 16 + m16;
        const ushort* Xrow = Xb + (size_t)rowc * D;
#pragma unroll
        for (int s2 = 0; s2 < 4; s2++) {
            short8 af = *(const short8*)&Xrow[s2 * 32 + q * 8];
            const short* bbase = Wcp + ((size_t)((16 + s2) * 4 + q) * BN + nbase + m16) * 8;
#pragma unroll
            for (int nf = 0; nf < NFW; nf++) {
                short8 bf = *(const short8*)(bbase + nf * 128);
                acc2[nf] = __builtin_amdgcn_mfma_f32_16x16x32_bf16(af, bf, acc2[nf], 0, 0, 0);
            }
        }
    }

    __syncthreads();

    // ---- phase 2: 32x512 @ 512xBN from LDS, one quadrant per wave ----
#pragma unroll 4
    for (int ks = 0; ks < 16; ks++) {
        int kq = ks * 4 + q;
        short8 af = *(const short8*)&At[(kq * 32 + ((mt * 16 + m16) ^ (kq & 7))) * 8];
        const short* bbase = Wcp + ((size_t)kq * BN + nbase + m16) * 8;
#pragma unroll
        for (int nf = 0; nf < NFW; nf++) {
            short8 bf = *(const short8*)(bbase + nf * 128);
            acc2[nf] = __builtin_amdgcn_mfma_f32_16x16x32_bf16(af, bf, acc2[nf], 0, 0, 0);
        }
    }

    // ---- epilogue ----
#pragma unroll
    for (int nf = 0; nf < NFW; nf++) {
        int n = nbase + nf * 16 + m16;
        float b = bias[n];
#pragma unroll
        for (int r = 0; r < 4; r++) {
            int m = v0 + mt * 16 + q * 4 + r;
            float vv = acc2[nf][r] + b;
            if (RELU) vv = fmaxf(vv, 0.0f);
            if (OUT_BF16) ((ushort*)Cout)[(size_t)m * BN + n] = f2bf(vv);
            else          ((float*)Cout)[(size_t)m * BN + n]  = vv;
        }
    }
}

// ---------------------------------------------------------------------------
extern "C" void kernel_launch(void* const* d_in, const int* in_sizes, int n_in,
                              void* d_out, int out_size, void* d_ws, size_t ws_size,
                              hipStream_t stream) {
    const float* x     = (const float*)d_in[0];
    const int*   ei    = (const int*)d_in[1];
    const int*   et    = (const int*)d_in[2];
    const float* W1    = (const float*)d_in[3];
    const float* root1 = (const float*)d_in[4];
    const float* b1    = (const float*)d_in[5];
    const float* W2    = (const float*)d_in[6];
    const float* root2 = (const float*)d_in[7];
    const float* b2    = (const float*)d_in[8];
    const int* srcp = ei;
    const int* dstp = ei + NE;
    float* out = (float*)d_out;

    // Workspace layout (all segments 16-B aligned)
    short*  Wp1  = (short*)d_ws;                          // 640*128 bf16
    short*  Wp2  = Wp1 + (size_t)KCAT * D;                // 640*96  bf16
    ushort* Xb   = (ushort*)(Wp2 + (size_t)KCAT * DOUT2); // NN*128 bf16
    ushort* h    = Xb + (size_t)NN * D;                   // NN*128 bf16
    float*  cnt  = (float*)(h + (size_t)NN * D);          // NN*4 f32
    int*    off  = (int*)(cnt + (size_t)NN * NREL);       // NN+1
    int*    fill = off + (NN + 1);                        // NN*4 (per dst,rel)
    int*    bsum = fill + (size_t)NN * 4;                 // 128
    int*    srcpk= bsum + 128;                            // NE

    // ---- prep (shared by both layers) ----
    {
        const int S = (NN * NREL) / 4 + NN + (NN * D) / 4 + KCAT * D + KCAT * DOUT2;
        prep0<<<(S + 255) / 256, 256, 0, stream>>>(x, Xb, W1, root1, Wp1,
                                                   W2, root2, Wp2, cnt, fill);
    }
    count_deg<<<(NE + 255) / 256, 256, 0, stream>>>(dstp, et, cnt);
    scan1<<<SCAN_B, 256, 0, stream>>>(cnt, bsum);
    scan2<<<1, 128, 0, stream>>>(bsum);
    scan3<<<SCAN_B, 256, 0, stream>>>(cnt, bsum, off);
    bucket_edges<<<(NE + 255) / 256, 256, 0, stream>>>(srcp, dstp, et, off, fill,
                                                       srcpk, cnt);

    const int fblocks = NN / 32;  // 3125 (exact)

    // ---- Layer 1: h = relu(agg(x) @ W1cat + b1), bf16 out ----
    rgcn_fused<128, true, true><<<fblocks, 256, 0, stream>>>(
        Xb, srcpk, off, cnt, Wp1, b1, h, NN);
    // ---- Layer 2: out = agg(h) @ W2cat + b2, f32 out ----
    rgcn_fused<96, false, false><<<fblocks, 256, 0, stream>>>(
        h, srcpk, off, cnt, Wp2, b2, out, NN);
}

// Round 11
// 340.390 us; speedup vs baseline: 1.3566x; 1.0777x over previous
//
#include <hip/hip_runtime.h>

// Problem constants
#define NN 100000      // nodes
#define NE 600000      // edges
#define D  128         // feature dim in (both layers)
#define DOUT2 96
#define NREL 4
#define KREL 512       // NREL * D
#define KCAT 640       // KREL + D
#define SCAN_B 98      // ceil(NN / 1024)

typedef short short8 __attribute__((ext_vector_type(8)));   // 8 bf16
typedef float f32x4  __attribute__((ext_vector_type(4)));

// fp32 -> bf16 round-to-nearest-even (finite inputs)
__device__ __forceinline__ ushort f2bf(float x) {
    unsigned u = __builtin_bit_cast(unsigned, x);
    u += 0x7fffu + ((u >> 16) & 1u);
    return (ushort)(u >> 16);
}
__device__ __forceinline__ float bfhi(unsigned u) {
    return __builtin_bit_cast(float, u & 0xffff0000u);
}
__device__ __forceinline__ float bflo(unsigned u) {
    return __builtin_bit_cast(float, u << 16);
}

// ---------------------------------------------------------------------------
// Fused independent prep: zero cnt, zero fill, x->bf16, pack Wcp1, pack Wcp2.
__global__ void prep0(const float* __restrict__ x, ushort* __restrict__ Xb,
                      const float* __restrict__ W1, const float* __restrict__ root1,
                      short* __restrict__ Wp1,
                      const float* __restrict__ W2, const float* __restrict__ root2,
                      short* __restrict__ Wp2,
                      float* __restrict__ cnt, int* __restrict__ fill) {
    int i = blockIdx.x * 256 + threadIdx.x;
    const int S0 = (NN * NREL) / 4;   // 100000 float4 zeros of cnt
    const int S1 = NN / 4;            // 25000 int4 zeros of fill
    const int S2 = (NN * D) / 4;      // 3200000 float4->ushort4 converts
    const int S3 = KCAT * D;          // 81920 pack1 elements
    const int S4 = KCAT * DOUT2;      // 61440 pack2 elements
    if (i < S0) { ((float4*)cnt)[i] = make_float4(0.f, 0.f, 0.f, 0.f); return; }
    i -= S0;
    if (i < S1) { ((int4*)fill)[i] = make_int4(0, 0, 0, 0); return; }
    i -= S1;
    if (i < S2) {
        float4 v = ((const float4*)x)[i];
        ushort4 o;
        o.x = f2bf(v.x); o.y = f2bf(v.y); o.z = f2bf(v.z); o.w = f2bf(v.w);
        ((ushort4*)Xb)[i] = o;
        return;
    }
    i -= S2;
    if (i < S3) {   // Wcp[kq][n][j] = Wcat[kq*8+j][n], BN = 128
        int j = i & 7, rest = i >> 3;
        int n = rest % D, kq = rest / D;
        int k = kq * 8 + j;
        float v = (k < KREL) ? W1[(size_t)k * D + n] : root1[(size_t)(k - KREL) * D + n];
        Wp1[i] = (short)f2bf(v);
        return;
    }
    i -= S3;
    if (i < S4) {   // BN = 96
        int j = i & 7, rest = i >> 3;
        int n = rest % DOUT2, kq = rest / DOUT2;
        int k = kq * 8 + j;
        float v = (k < KREL) ? W2[(size_t)k * DOUT2 + n] : root2[(size_t)(k - KREL) * DOUT2 + n];
        Wp2[i] = (short)f2bf(v);
        return;
    }
}

// ---------------------------------------------------------------------------
// cnt[v][r] = #edges with dst=v, etype=r
__global__ void count_deg(const int* __restrict__ dst,
                          const int* __restrict__ et,
                          float* __restrict__ cnt) {
    int e = blockIdx.x * blockDim.x + threadIdx.x;
    if (e < NE) unsafeAtomicAdd(&cnt[dst[e] * NREL + et[e]], 1.0f);
}

// ---------------------------------------------------------------------------
// Prefix sum of per-node degree -> off[0..NN] (3-kernel scan)
__global__ void scan1(const float* __restrict__ cnt, int* __restrict__ bsum) {
    __shared__ int s[256];
    int tid = threadIdx.x;
    int base = blockIdx.x * 1024 + tid * 4;
    int t = 0;
    for (int i = 0; i < 4; i++) {
        int v = base + i;
        if (v < NN) {
            float4 c = *(const float4*)&cnt[(size_t)v * 4];
            t += (int)(c.x + c.y + c.z + c.w);
        }
    }
    s[tid] = t; __syncthreads();
    for (int o = 128; o > 0; o >>= 1) {
        if (tid < o) s[tid] += s[tid + o];
        __syncthreads();
    }
    if (tid == 0) bsum[blockIdx.x] = s[0];
}

__global__ void scan2(int* __restrict__ bsum) {  // 1 block of 128; exclusive in-place
    __shared__ int s[128];
    int tid = threadIdx.x;
    int mine = (tid < SCAN_B) ? bsum[tid] : 0;
    s[tid] = mine; __syncthreads();
    for (int o = 1; o < 128; o <<= 1) {
        int v = (tid >= o) ? s[tid - o] : 0;
        __syncthreads();
        s[tid] += v;
        __syncthreads();
    }
    if (tid < SCAN_B) bsum[tid] = s[tid] - mine;
}

__global__ void scan3(const float* __restrict__ cnt, const int* __restrict__ bsum,
                      int* __restrict__ off) {
    __shared__ int s[256];
    int tid = threadIdx.x;
    int base = blockIdx.x * 1024 + tid * 4;
    int d[4]; int t = 0;
    for (int i = 0; i < 4; i++) {
        int v = base + i; d[i] = 0;
        if (v < NN) {
            float4 c = *(const float4*)&cnt[(size_t)v * 4];
            d[i] = (int)(c.x + c.y + c.z + c.w);
        }
        t += d[i];
    }
    int mine = t;
    s[tid] = t; __syncthreads();
    for (int o = 1; o < 256; o <<= 1) {
        int v = (tid >= o) ? s[tid - o] : 0;
        __syncthreads();
        s[tid] += v;
        __syncthreads();
    }
    int ex = s[tid] - mine + bsum[blockIdx.x];
    for (int i = 0; i < 4; i++) {
        int v = base + i;
        if (v < NN) { off[v] = ex; ex += d[i]; }
    }
    if (blockIdx.x == 0 && tid == 0) off[NN] = NE;
}

// ---------------------------------------------------------------------------
// Bucket edges by dst; packed (src<<2)|etype
__global__ void bucket_edges(const int* __restrict__ src, const int* __restrict__ dst,
                             const int* __restrict__ et, const int* __restrict__ off,
                             int* __restrict__ fill, int* __restrict__ srcpk) {
    int e = blockIdx.x * blockDim.x + threadIdx.x;
    if (e >= NE) return;
    int dn = dst[e];
    int pos = off[dn] + atomicAdd(&fill[dn], 1);
    srcpk[pos] = (src[e] << 2) | et[e];
}

// ---------------------------------------------------------------------------
// Fused RGCN layer — 16-node block, raised-occupancy variant (R11).
// Block = 256 threads (4 waves), 16 dst nodes, one 16 KB LDS tile
// [kq16=64][node=16][8 bf16], node slot XOR-swizzled by kq&7 (measured:
// SQ_LDS_BANK_CONFLICT 5.6M -> 0).
// CAUSAL MODEL (R10 confirmed): kernel is gather-MLP-bound. Cutting VALU
// 35% while dropping loads-in-flight 4 -> 1.3 made it 24% SLOWER (R10);
// per-chain depth >4 spills (R2/R3/R8); the remaining lever is wave count.
// R9 proved occupancy can reach 75% with 16KB LDS, but (256,8) forced a
// 32-VGPR alloc -> 294 MB spill. THIS variant: __launch_bounds__(256,6)
// -> VGPR cap ~85 >= proven 48-64 body need, 6 blocks x 16KB = 96KB LDS,
// residency ceiling 20 -> 24 waves/CU with NO spill.
// Spill tripwire: WRITE_SIZE must stay == output size (25000 KiB layer 1);
// VGPR_Count must be 48-64 (a 32 means the cap misfired -> revert).
//   Phase 1: 16 quarter-wave chains, ONE node each; 4-wide unrolled gather
//            batches (R5 body, proven no-spill). fp32 acc, predicated
//            per-relation scales.
//   Root MFMAs (global-only operands) run BEFORE the barrier.
//   Phase 2: 16 x BN from 640 k. Wave w owns col-frags {w, 4+w}; for
//            BN=96 the second frag is skipped by a wave-uniform branch.
template <int BN, bool RELU, bool OUT_BF16>
__global__ __launch_bounds__(256, 6) void rgcn_fused(
    const ushort* __restrict__ Xb,   // [M,128] bf16
    const int*   __restrict__ srcpk, // [NE] bucketed, (src<<2)|t
    const int*   __restrict__ off,   // [M+1]
    const float* __restrict__ cnt,   // [M,4]
    const short* __restrict__ Wcp,   // [80][BN][8] bf16
    const float* __restrict__ bias,  // [BN]
    void*        __restrict__ Cout,  // [M,BN] bf16 or f32
    int M) {
    __shared__ short At[64 * 16 * 8];        // 16 KB

    const int tid  = threadIdx.x;
    const int wave = tid >> 6;
    const int lane = tid & 63;
    const int l    = lane & 15;     // phase1: feat group / phase2: m16 (col)
    const int qw   = lane >> 4;     // phase1: quarter / phase2: k-quad q
    const int g    = wave * 4 + qw; // chain id 0..15 == node index in tile
    const int v0   = blockIdx.x * 16;

    // ---- phase 1: one node per chain ----
    {
        int v = v0 + g;             // NN % 16 == 0 -> always < M
        float acc[4][8];
#pragma unroll
        for (int r = 0; r < 4; r++)
#pragma unroll
            for (int j = 0; j < 8; j++) acc[r][j] = 0.0f;

        float4 c4 = *(const float4*)&cnt[(size_t)v * 4];
        float nrm0 = 1.0f / fmaxf(c4.x, 1.0f);
        float nrm1 = 1.0f / fmaxf(c4.y, 1.0f);
        float nrm2 = 1.0f / fmaxf(c4.z, 1.0f);
        float nrm3 = 1.0f / fmaxf(c4.w, 1.0f);
        int e = off[v], end = off[v + 1];

#define EDGE_ACC(PK, XB) {                                                  \
        int t_ = (PK) & 3;                                                  \
        float s0 = (t_ == 0) ? nrm0 : 0.0f;                                 \
        float s1 = (t_ == 1) ? nrm1 : 0.0f;                                 \
        float s2 = (t_ == 2) ? nrm2 : 0.0f;                                 \
        float s3 = (t_ == 3) ? nrm3 : 0.0f;                                 \
        float xf[8];                                                        \
        xf[0] = bflo(XB.x); xf[1] = bfhi(XB.x);                             \
        xf[2] = bflo(XB.y); xf[3] = bfhi(XB.y);                             \
        xf[4] = bflo(XB.z); xf[5] = bfhi(XB.z);                             \
        xf[6] = bflo(XB.w); xf[7] = bfhi(XB.w);                             \
        _Pragma("unroll")                                                   \
        for (int j = 0; j < 8; j++) {                                       \
            acc[0][j] += s0 * xf[j];                                        \
            acc[1][j] += s1 * xf[j];                                        \
            acc[2][j] += s2 * xf[j];                                        \
            acc[3][j] += s3 * xf[j];                                        \
        } }

        for (; e + 3 < end; e += 4) {   // 4 gathers in flight per chain
            int p0 = srcpk[e],     p1 = srcpk[e + 1];
            int p2 = srcpk[e + 2], p3 = srcpk[e + 3];
            uint4 x0 = *(const uint4*)&Xb[(size_t)(p0 >> 2) * D + l * 8];
            uint4 x1 = *(const uint4*)&Xb[(size_t)(p1 >> 2) * D + l * 8];
            uint4 x2 = *(const uint4*)&Xb[(size_t)(p2 >> 2) * D + l * 8];
            uint4 x3 = *(const uint4*)&Xb[(size_t)(p3 >> 2) * D + l * 8];
            EDGE_ACC(p0, x0); EDGE_ACC(p1, x1);
            EDGE_ACC(p2, x2); EDGE_ACC(p3, x3);
        }
        for (; e < end; e++) {
            int p0 = srcpk[e];
            uint4 x0 = *(const uint4*)&Xb[(size_t)(p0 >> 2) * D + l * 8];
            EDGE_ACC(p0, x0);
        }
#undef EDGE_ACC

        // stage to LDS in A-frag order: kq16 = r*16 + l, node slot XOR-swizzled
        // by kq&7 -> ds_write_b128 spreads over banks (measured 0 conflicts)
#pragma unroll
        for (int r = 0; r < 4; r++) {
            short8 w;
#pragma unroll
            for (int j = 0; j < 8; j++) w[j] = (short)f2bf(acc[r][j]);
            int kq = r * 16 + l;
            *(short8*)&At[(kq * 16 + (g ^ (kq & 7))) * 8] = w;
        }
    }

    // ---- phase 2 setup: wave w owns col-frags nb0 = w*16 and nb1 = 64+w*16
    const int m16  = l;
    const int q    = qw;
    const int nb0  = wave * 16;
    const int nb1  = 64 + wave * 16;
    const bool has1 = (nb1 < BN);   // wave-uniform; false for waves 2,3 @ BN=96
    f32x4 a0 = (f32x4)0.0f, a1 = (f32x4)0.0f;

    // root part first (k = 512..639, global-only operands): phase-1 registers
    // are dead here; fast waves do these MFMAs while slow chains gather.
    {
        int rowc = v0 + m16;
        const ushort* Xrow = Xb + (size_t)rowc * D;
#pragma unroll
        for (int s2 = 0; s2 < 4; s2++) {
            short8 af = *(const short8*)&Xrow[s2 * 32 + q * 8];
            size_t kqb = (size_t)((16 + s2) * 4 + q) * BN;
            a0 = __builtin_amdgcn_mfma_f32_16x16x32_bf16(
                af, *(const short8*)(Wcp + (kqb + nb0 + m16) * 8), a0, 0, 0, 0);
            if (has1)
                a1 = __builtin_amdgcn_mfma_f32_16x16x32_bf16(
                    af, *(const short8*)(Wcp + (kqb + nb1 + m16) * 8), a1, 0, 0, 0);
        }
    }

    __syncthreads();

    // ---- phase 2: 16x512 @ 512xBN from LDS ----
#pragma unroll 4
    for (int ks = 0; ks < 16; ks++) {
        int kq = ks * 4 + q;
        short8 af = *(const short8*)&At[(kq * 16 + (m16 ^ (kq & 7))) * 8];
        size_t kqb = (size_t)kq * BN;
        a0 = __builtin_amdgcn_mfma_f32_16x16x32_bf16(
            af, *(const short8*)(Wcp + (kqb + nb0 + m16) * 8), a0, 0, 0, 0);
        if (has1)
            a1 = __builtin_amdgcn_mfma_f32_16x16x32_bf16(
                af, *(const short8*)(Wcp + (kqb + nb1 + m16) * 8), a1, 0, 0, 0);
    }

    // ---- epilogue ----
    {
        int n = nb0 + m16;
        float b = bias[n];
#pragma unroll
        for (int r = 0; r < 4; r++) {
            int m = v0 + q * 4 + r;
            float vv = a0[r] + b;
            if (RELU) vv = fmaxf(vv, 0.0f);
            if (OUT_BF16) ((ushort*)Cout)[(size_t)m * BN + n] = f2bf(vv);
            else          ((float*)Cout)[(size_t)m * BN + n]  = vv;
        }
    }
    if (has1) {
        int n = nb1 + m16;
        float b = bias[n];
#pragma unroll
        for (int r = 0; r < 4; r++) {
            int m = v0 + q * 4 + r;
            float vv = a1[r] + b;
            if (RELU) vv = fmaxf(vv, 0.0f);
            if (OUT_BF16) ((ushort*)Cout)[(size_t)m * BN + n] = f2bf(vv);
            else          ((float*)Cout)[(size_t)m * BN + n]  = vv;
        }
    }
}

// ---------------------------------------------------------------------------
extern "C" void kernel_launch(void* const* d_in, const int* in_sizes, int n_in,
                              void* d_out, int out_size, void* d_ws, size_t ws_size,
                              hipStream_t stream) {
    const float* x     = (const float*)d_in[0];
    const int*   ei    = (const int*)d_in[1];
    const int*   et    = (const int*)d_in[2];
    const float* W1    = (const float*)d_in[3];
    const float* root1 = (const float*)d_in[4];
    const float* b1    = (const float*)d_in[5];
    const float* W2    = (const float*)d_in[6];
    const float* root2 = (const float*)d_in[7];
    const float* b2    = (const float*)d_in[8];
    const int* srcp = ei;
    const int* dstp = ei + NE;
    float* out = (float*)d_out;

    // Workspace layout (all segments 16-B aligned)
    short*  Wp1  = (short*)d_ws;                          // 640*128 bf16
    short*  Wp2  = Wp1 + (size_t)KCAT * D;                // 640*96  bf16
    ushort* Xb   = (ushort*)(Wp2 + (size_t)KCAT * DOUT2); // NN*128 bf16
    ushort* h    = Xb + (size_t)NN * D;                   // NN*128 bf16
    float*  cnt  = (float*)(h + (size_t)NN * D);          // NN*4 f32
    int*    off  = (int*)(cnt + (size_t)NN * NREL);       // NN+1
    int*    fill = off + (NN + 1);                        // NN
    int*    bsum = fill + NN;                             // 128
    int*    srcpk= bsum + 128;                            // NE

    // ---- prep (shared by both layers) ----
    {
        const int S = (NN * NREL) / 4 + NN / 4 + (NN * D) / 4 + KCAT * D + KCAT * DOUT2;
        prep0<<<(S + 255) / 256, 256, 0, stream>>>(x, Xb, W1, root1, Wp1,
                                                   W2, root2, Wp2, cnt, fill);
    }
    count_deg<<<(NE + 255) / 256, 256, 0, stream>>>(dstp, et, cnt);
    scan1<<<SCAN_B, 256, 0, stream>>>(cnt, bsum);
    scan2<<<1, 128, 0, stream>>>(bsum);
    scan3<<<SCAN_B, 256, 0, stream>>>(cnt, bsum, off);
    bucket_edges<<<(NE + 255) / 256, 256, 0, stream>>>(srcp, dstp, et, off, fill, srcpk);

    const int fblocks = NN / 16;  // 6250 (exact)

    // ---- Layer 1: h = relu(agg(x) @ W1cat + b1), bf16 out ----
    rgcn_fused<128, true, true><<<fblocks, 256, 0, stream>>>(
        Xb, srcpk, off, cnt, Wp1, b1, h, NN);
    // ---- Layer 2: out = agg(h) @ W2cat + b2, f32 out ----
    rgcn_fused<96, false, false><<<fblocks, 256, 0, stream>>>(
        h, srcpk, off, cnt, Wp2, b2, out, NN);
}

// Round 12
// 310.709 us; speedup vs baseline: 1.4862x; 1.0955x over previous
//
#include <hip/hip_runtime.h>

// Problem constants
#define NN 100000      // nodes
#define NE 600000      // edges
#define D  128         // feature dim in (both layers)
#define DOUT2 96
#define NREL 4
#define KREL 512       // NREL * D
#define KCAT 640       // KREL + D
#define SCAN_B 98      // ceil(NN / 1024)
#define EMAX 1024      // staged edge-index capacity per block (mean 192, 60 sigma)

typedef short short8 __attribute__((ext_vector_type(8)));   // 8 bf16
typedef float f32x4  __attribute__((ext_vector_type(4)));

// fp32 -> bf16 round-to-nearest-even (finite inputs)
__device__ __forceinline__ ushort f2bf(float x) {
    unsigned u = __builtin_bit_cast(unsigned, x);
    u += 0x7fffu + ((u >> 16) & 1u);
    return (ushort)(u >> 16);
}
__device__ __forceinline__ float bfhi(unsigned u) {
    return __builtin_bit_cast(float, u & 0xffff0000u);
}
__device__ __forceinline__ float bflo(unsigned u) {
    return __builtin_bit_cast(float, u << 16);
}

// ---------------------------------------------------------------------------
// Fused independent prep: zero cnt, zero fill, x->bf16, pack Wcp1, pack Wcp2.
__global__ void prep0(const float* __restrict__ x, ushort* __restrict__ Xb,
                      const float* __restrict__ W1, const float* __restrict__ root1,
                      short* __restrict__ Wp1,
                      const float* __restrict__ W2, const float* __restrict__ root2,
                      short* __restrict__ Wp2,
                      float* __restrict__ cnt, int* __restrict__ fill) {
    int i = blockIdx.x * 256 + threadIdx.x;
    const int S0 = (NN * NREL) / 4;   // 100000 float4 zeros of cnt
    const int S1 = NN / 4;            // 25000 int4 zeros of fill
    const int S2 = (NN * D) / 4;      // 3200000 float4->ushort4 converts
    const int S3 = KCAT * D;          // 81920 pack1 elements
    const int S4 = KCAT * DOUT2;      // 61440 pack2 elements
    if (i < S0) { ((float4*)cnt)[i] = make_float4(0.f, 0.f, 0.f, 0.f); return; }
    i -= S0;
    if (i < S1) { ((int4*)fill)[i] = make_int4(0, 0, 0, 0); return; }
    i -= S1;
    if (i < S2) {
        float4 v = ((const float4*)x)[i];
        ushort4 o;
        o.x = f2bf(v.x); o.y = f2bf(v.y); o.z = f2bf(v.z); o.w = f2bf(v.w);
        ((ushort4*)Xb)[i] = o;
        return;
    }
    i -= S2;
    if (i < S3) {   // Wcp[kq][n][j] = Wcat[kq*8+j][n], BN = 128
        int j = i & 7, rest = i >> 3;
        int n = rest % D, kq = rest / D;
        int k = kq * 8 + j;
        float v = (k < KREL) ? W1[(size_t)k * D + n] : root1[(size_t)(k - KREL) * D + n];
        Wp1[i] = (short)f2bf(v);
        return;
    }
    i -= S3;
    if (i < S4) {   // BN = 96
        int j = i & 7, rest = i >> 3;
        int n = rest % DOUT2, kq = rest / DOUT2;
        int k = kq * 8 + j;
        float v = (k < KREL) ? W2[(size_t)k * DOUT2 + n] : root2[(size_t)(k - KREL) * DOUT2 + n];
        Wp2[i] = (short)f2bf(v);
        return;
    }
}

// ---------------------------------------------------------------------------
// cnt[v][r] = #edges with dst=v, etype=r
__global__ void count_deg(const int* __restrict__ dst,
                          const int* __restrict__ et,
                          float* __restrict__ cnt) {
    int e = blockIdx.x * blockDim.x + threadIdx.x;
    if (e < NE) unsafeAtomicAdd(&cnt[dst[e] * NREL + et[e]], 1.0f);
}

// ---------------------------------------------------------------------------
// Prefix sum of per-node degree -> off[0..NN] (3-kernel scan)
__global__ void scan1(const float* __restrict__ cnt, int* __restrict__ bsum) {
    __shared__ int s[256];
    int tid = threadIdx.x;
    int base = blockIdx.x * 1024 + tid * 4;
    int t = 0;
    for (int i = 0; i < 4; i++) {
        int v = base + i;
        if (v < NN) {
            float4 c = *(const float4*)&cnt[(size_t)v * 4];
            t += (int)(c.x + c.y + c.z + c.w);
        }
    }
    s[tid] = t; __syncthreads();
    for (int o = 128; o > 0; o >>= 1) {
        if (tid < o) s[tid] += s[tid + o];
        __syncthreads();
    }
    if (tid == 0) bsum[blockIdx.x] = s[0];
}

__global__ void scan2(int* __restrict__ bsum) {  // 1 block of 128; exclusive in-place
    __shared__ int s[128];
    int tid = threadIdx.x;
    int mine = (tid < SCAN_B) ? bsum[tid] : 0;
    s[tid] = mine; __syncthreads();
    for (int o = 1; o < 128; o <<= 1) {
        int v = (tid >= o) ? s[tid - o] : 0;
        __syncthreads();
        s[tid] += v;
        __syncthreads();
    }
    if (tid < SCAN_B) bsum[tid] = s[tid] - mine;
}

__global__ void scan3(const float* __restrict__ cnt, const int* __restrict__ bsum,
                      int* __restrict__ off) {
    __shared__ int s[256];
    int tid = threadIdx.x;
    int base = blockIdx.x * 1024 + tid * 4;
    int d[4]; int t = 0;
    for (int i = 0; i < 4; i++) {
        int v = base + i; d[i] = 0;
        if (v < NN) {
            float4 c = *(const float4*)&cnt[(size_t)v * 4];
            d[i] = (int)(c.x + c.y + c.z + c.w);
        }
        t += d[i];
    }
    int mine = t;
    s[tid] = t; __syncthreads();
    for (int o = 1; o < 256; o <<= 1) {
        int v = (tid >= o) ? s[tid - o] : 0;
        __syncthreads();
        s[tid] += v;
        __syncthreads();
    }
    int ex = s[tid] - mine + bsum[blockIdx.x];
    for (int i = 0; i < 4; i++) {
        int v = base + i;
        if (v < NN) { off[v] = ex; ex += d[i]; }
    }
    if (blockIdx.x == 0 && tid == 0) off[NN] = NE;
}

// ---------------------------------------------------------------------------
// Bucket edges by dst; packed (src<<2)|etype
__global__ void bucket_edges(const int* __restrict__ src, const int* __restrict__ dst,
                             const int* __restrict__ et, const int* __restrict__ off,
                             int* __restrict__ fill, int* __restrict__ srcpk) {
    int e = blockIdx.x * blockDim.x + threadIdx.x;
    if (e >= NE) return;
    int dn = dst[e];
    int pos = off[dn] + atomicAdd(&fill[dn], 1);
    srcpk[pos] = (src[e] << 2) | et[e];
}

// ---------------------------------------------------------------------------
// Fused RGCN layer — R5 frame + LDS-staged edge indices (R12).
// Block = 256 threads (4 waves), 32 dst nodes, 32 KB A-tile + 4 KB idx LDS.
// CAUSAL MODEL (R6..R11): bound by serial memory round trips per chain.
// Occupancy 36->57->75% flat; VALU -35% made it slower (R10); depth>4
// spills (R2/R3/R8). Each 4-edge batch = TWO dependent trips: global idx
// load -> wait -> row gather -> wait. R12 removes the first: the block's
// srcpk segment (~192 ints) is staged cooperatively into LDS up front,
// so batches read indices via ds_read (~100cy, overlappable) and go
// straight to the row gathers. RTs/node ~5-6 -> ~3-4.
// Fallback: >EMAX edges/block (60-sigma event) reads global (block-uniform
// branch, correctness only).
// Spill tripwire: WRITE_SIZE must stay == output (25000 KiB L1); VGPR 48-72.
//   Phase 1 body, XOR-swizzled staging, root-MFMA hoist, phase-2 quadrant
//   split: byte-identical to R5 (measured 81.3 us, 0 conflicts, no spill).
template <int BN, bool RELU, bool OUT_BF16>
__global__ __launch_bounds__(256, 4) void rgcn_fused(
    const ushort* __restrict__ Xb,   // [M,128] bf16
    const int*   __restrict__ srcpk, // [NE] bucketed, (src<<2)|t
    const int*   __restrict__ off,   // [M+1]
    const float* __restrict__ cnt,   // [M,4]
    const short* __restrict__ Wcp,   // [80][BN][8] bf16
    const float* __restrict__ bias,  // [BN]
    void*        __restrict__ Cout,  // [M,BN] bf16 or f32
    int M) {
    constexpr int NFW = (BN / 16 + 1) / 2;   // frags per wave: 4 (BN=128) / 3 (BN=96)
    __shared__ short At[64 * 32 * 8];        // 32 KB
    __shared__ int   eidx[EMAX];             // 4 KB staged (src<<2)|t

    const int tid  = threadIdx.x;
    const int wave = tid >> 6;
    const int lane = tid & 63;
    const int l    = lane & 15;     // phase1: feat group / phase2: m16
    const int qw   = lane >> 4;     // phase1: quarter / phase2: k-quad q
    const int g    = wave * 4 + qw; // chain id 0..15
    const int v0   = blockIdx.x * 32;

    // ---- stage the block's edge indices into LDS (coalesced, 1-2 iters) ----
    const int ebase = off[v0];
    const int nE    = off[v0 + 32] - ebase;
    const bool useL = (nE <= EMAX);
    if (useL) {
        for (int i = tid; i < nE; i += 256) eidx[i] = srcpk[ebase + i];
    }
    __syncthreads();

    // ---- phase 1: aggregate 32 nodes (2 per chain) ----
    // PHASE1_BODY(LOADI): per-node aggregation with index source LOADI(e).
#define EDGE_ACC(PK, XB) {                                                  \
        int t_ = (PK) & 3;                                                  \
        float s0 = (t_ == 0) ? nrm0 : 0.0f;                                 \
        float s1 = (t_ == 1) ? nrm1 : 0.0f;                                 \
        float s2 = (t_ == 2) ? nrm2 : 0.0f;                                 \
        float s3 = (t_ == 3) ? nrm3 : 0.0f;                                 \
        float xf[8];                                                        \
        xf[0] = bflo(XB.x); xf[1] = bfhi(XB.x);                             \
        xf[2] = bflo(XB.y); xf[3] = bfhi(XB.y);                             \
        xf[4] = bflo(XB.z); xf[5] = bfhi(XB.z);                             \
        xf[6] = bflo(XB.w); xf[7] = bfhi(XB.w);                             \
        _Pragma("unroll")                                                   \
        for (int j = 0; j < 8; j++) {                                       \
            acc[0][j] += s0 * xf[j];                                        \
            acc[1][j] += s1 * xf[j];                                        \
            acc[2][j] += s2 * xf[j];                                        \
            acc[3][j] += s3 * xf[j];                                        \
        } }

#define PHASE1_BODY(LOADI)                                                  \
    _Pragma("unroll")                                                       \
    for (int half = 0; half < 2; half++) {                                  \
        int nv = g + half * 16;                                             \
        int v  = v0 + nv;                                                   \
        float acc[4][8];                                                    \
        _Pragma("unroll")                                                   \
        for (int r = 0; r < 4; r++)                                         \
            _Pragma("unroll")                                               \
            for (int j = 0; j < 8; j++) acc[r][j] = 0.0f;                   \
        float4 c4 = *(const float4*)&cnt[(size_t)v * 4];                    \
        float nrm0 = 1.0f / fmaxf(c4.x, 1.0f);                              \
        float nrm1 = 1.0f / fmaxf(c4.y, 1.0f);                              \
        float nrm2 = 1.0f / fmaxf(c4.z, 1.0f);                              \
        float nrm3 = 1.0f / fmaxf(c4.w, 1.0f);                              \
        int e = off[v], end = off[v + 1];                                   \
        for (; e + 3 < end; e += 4) {                                       \
            int p0 = LOADI(e),     p1 = LOADI(e + 1);                       \
            int p2 = LOADI(e + 2), p3 = LOADI(e + 3);                       \
            uint4 x0 = *(const uint4*)&Xb[(size_t)(p0 >> 2) * D + l * 8];   \
            uint4 x1 = *(const uint4*)&Xb[(size_t)(p1 >> 2) * D + l * 8];   \
            uint4 x2 = *(const uint4*)&Xb[(size_t)(p2 >> 2) * D + l * 8];   \
            uint4 x3 = *(const uint4*)&Xb[(size_t)(p3 >> 2) * D + l * 8];   \
            EDGE_ACC(p0, x0); EDGE_ACC(p1, x1);                             \
            EDGE_ACC(p2, x2); EDGE_ACC(p3, x3);                             \
        }                                                                   \
        for (; e < end; e++) {                                              \
            int p0 = LOADI(e);                                              \
            uint4 x0 = *(const uint4*)&Xb[(size_t)(p0 >> 2) * D + l * 8];   \
            EDGE_ACC(p0, x0);                                               \
        }                                                                   \
        _Pragma("unroll")                                                   \
        for (int r = 0; r < 4; r++) {                                       \
            short8 w;                                                       \
            _Pragma("unroll")                                               \
            for (int j = 0; j < 8; j++) w[j] = (short)f2bf(acc[r][j]);      \
            int kq = r * 16 + l;                                            \
            *(short8*)&At[(kq * 32 + (nv ^ (kq & 7))) * 8] = w;             \
        }                                                                   \
    }

#define LOADI_LDS(E)  eidx[(E) - ebase]
#define LOADI_GLB(E)  srcpk[(E)]
    if (useL) { PHASE1_BODY(LOADI_LDS) }
    else      { PHASE1_BODY(LOADI_GLB) }
#undef LOADI_LDS
#undef LOADI_GLB
#undef PHASE1_BODY
#undef EDGE_ACC

    // ---- phase 2 setup ----
    const int m16   = l;
    const int q     = qw;
    const int mt    = wave & 1;           // m-half (16 nodes)
    const int nbase = (wave >> 1) * NFW * 16;   // n-offset
    f32x4 acc2[NFW];
#pragma unroll
    for (int i = 0; i < NFW; i++) acc2[i] = (f32x4)0.0f;

    // root part first (k = 512..639, global-only operands): phase-1 registers
    // are dead here; fast waves do these MFMAs while slow chains gather.
    {
        int rowc = v0 + mt * 16 + m16;
        const ushort* Xrow = Xb + (size_t)rowc * D;
#pragma unroll
        for (int s2 = 0; s2 < 4; s2++) {
            short8 af = *(const short8*)&Xrow[s2 * 32 + q * 8];
            const short* bbase = Wcp + ((size_t)((16 + s2) * 4 + q) * BN + nbase + m16) * 8;
#pragma unroll
            for (int nf = 0; nf < NFW; nf++) {
                short8 bf = *(const short8*)(bbase + nf * 128);
                acc2[nf] = __builtin_amdgcn_mfma_f32_16x16x32_bf16(af, bf, acc2[nf], 0, 0, 0);
            }
        }
    }

    __syncthreads();

    // ---- phase 2: 32x512 @ 512xBN from LDS, one quadrant per wave ----
#pragma unroll 4
    for (int ks = 0; ks < 16; ks++) {
        int kq = ks * 4 + q;
        short8 af = *(const short8*)&At[(kq * 32 + ((mt * 16 + m16) ^ (kq & 7))) * 8];
        const short* bbase = Wcp + ((size_t)kq * BN + nbase + m16) * 8;
#pragma unroll
        for (int nf = 0; nf < NFW; nf++) {
            short8 bf = *(const short8*)(bbase + nf * 128);
            acc2[nf] = __builtin_amdgcn_mfma_f32_16x16x32_bf16(af, bf, acc2[nf], 0, 0, 0);
        }
    }

    // ---- epilogue ----
#pragma unroll
    for (int nf = 0; nf < NFW; nf++) {
        int n = nbase + nf * 16 + m16;
        float b = bias[n];
#pragma unroll
        for (int r = 0; r < 4; r++) {
            int m = v0 + mt * 16 + q * 4 + r;
            float vv = acc2[nf][r] + b;
            if (RELU) vv = fmaxf(vv, 0.0f);
            if (OUT_BF16) ((ushort*)Cout)[(size_t)m * BN + n] = f2bf(vv);
            else          ((float*)Cout)[(size_t)m * BN + n]  = vv;
        }
    }
}

// ---------------------------------------------------------------------------
extern "C" void kernel_launch(void* const* d_in, const int* in_sizes, int n_in,
                              void* d_out, int out_size, void* d_ws, size_t ws_size,
                              hipStream_t stream) {
    const float* x     = (const float*)d_in[0];
    const int*   ei    = (const int*)d_in[1];
    const int*   et    = (const int*)d_in[2];
    const float* W1    = (const float*)d_in[3];
    const float* root1 = (const float*)d_in[4];
    const float* b1    = (const float*)d_in[5];
    const float* W2    = (const float*)d_in[6];
    const float* root2 = (const float*)d_in[7];
    const float* b2    = (const float*)d_in[8];
    const int* srcp = ei;
    const int* dstp = ei + NE;
    float* out = (float*)d_out;

    // Workspace layout (all segments 16-B aligned)
    short*  Wp1  = (short*)d_ws;                          // 640*128 bf16
    short*  Wp2  = Wp1 + (size_t)KCAT * D;                // 640*96  bf16
    ushort* Xb   = (ushort*)(Wp2 + (size_t)KCAT * DOUT2); // NN*128 bf16
    ushort* h    = Xb + (size_t)NN * D;                   // NN*128 bf16
    float*  cnt  = (float*)(h + (size_t)NN * D);          // NN*4 f32
    int*    off  = (int*)(cnt + (size_t)NN * NREL);       // NN+1
    int*    fill = off + (NN + 1);                        // NN
    int*    bsum = fill + NN;                             // 128
    int*    srcpk= bsum + 128;                            // NE

    // ---- prep (shared by both layers) ----
    {
        const int S = (NN * NREL) / 4 + NN / 4 + (NN * D) / 4 + KCAT * D + KCAT * DOUT2;
        prep0<<<(S + 255) / 256, 256, 0, stream>>>(x, Xb, W1, root1, Wp1,
                                                   W2, root2, Wp2, cnt, fill);
    }
    count_deg<<<(NE + 255) / 256, 256, 0, stream>>>(dstp, et, cnt);
    scan1<<<SCAN_B, 256, 0, stream>>>(cnt, bsum);
    scan2<<<1, 128, 0, stream>>>(bsum);
    scan3<<<SCAN_B, 256, 0, stream>>>(cnt, bsum, off);
    bucket_edges<<<(NE + 255) / 256, 256, 0, stream>>>(srcp, dstp, et, off, fill, srcpk);

    const int fblocks = NN / 32;  // 3125 (exact)

    // ---- Layer 1: h = relu(agg(x) @ W1cat + b1), bf16 out ----
    rgcn_fused<128, true, true><<<fblocks, 256, 0, stream>>>(
        Xb, srcpk, off, cnt, Wp1, b1, h, NN);
    // ---- Layer 2: out = agg(h) @ W2cat + b2, f32 out ----
    rgcn_fused<96, false, false><<<fblocks, 256, 0, stream>>>(
        h, srcpk, off, cnt, Wp2, b2, out, NN);
}

// Round 13
// 305.326 us; speedup vs baseline: 1.5124x; 1.0176x over previous
//
#include <hip/hip_runtime.h>

// Problem constants
#define NN 100000      // nodes
#define NE 600000      // edges
#define D  128         // feature dim in (both layers)
#define DOUT2 96
#define NREL 4
#define KREL 512       // NREL * D
#define KCAT 640       // KREL + D
#define SCAN_B 98      // ceil(NN / 1024)
#define EMAX 1024      // staged edge-index capacity per block (mean 192)

typedef short short8 __attribute__((ext_vector_type(8)));   // 8 bf16
typedef float f32x4  __attribute__((ext_vector_type(4)));

// fp32 -> bf16 round-to-nearest-even (finite inputs)
__device__ __forceinline__ ushort f2bf(float x) {
    unsigned u = __builtin_bit_cast(unsigned, x);
    u += 0x7fffu + ((u >> 16) & 1u);
    return (ushort)(u >> 16);
}
__device__ __forceinline__ float bfhi(unsigned u) {
    return __builtin_bit_cast(float, u & 0xffff0000u);
}
__device__ __forceinline__ float bflo(unsigned u) {
    return __builtin_bit_cast(float, u << 16);
}

// ---------------------------------------------------------------------------
// Fused independent prep: zero cnt, zero fill, x->bf16, pack Wcp1, pack Wcp2.
__global__ void prep0(const float* __restrict__ x, ushort* __restrict__ Xb,
                      const float* __restrict__ W1, const float* __restrict__ root1,
                      short* __restrict__ Wp1,
                      const float* __restrict__ W2, const float* __restrict__ root2,
                      short* __restrict__ Wp2,
                      float* __restrict__ cnt, int* __restrict__ fill) {
    int i = blockIdx.x * 256 + threadIdx.x;
    const int S0 = (NN * NREL) / 4;   // 100000 float4 zeros of cnt
    const int S1 = NN / 4;            // 25000 int4 zeros of fill
    const int S2 = (NN * D) / 4;      // 3200000 float4->ushort4 converts
    const int S3 = KCAT * D;          // 81920 pack1 elements
    const int S4 = KCAT * DOUT2;      // 61440 pack2 elements
    if (i < S0) { ((float4*)cnt)[i] = make_float4(0.f, 0.f, 0.f, 0.f); return; }
    i -= S0;
    if (i < S1) { ((int4*)fill)[i] = make_int4(0, 0, 0, 0); return; }
    i -= S1;
    if (i < S2) {
        float4 v = ((const float4*)x)[i];
        ushort4 o;
        o.x = f2bf(v.x); o.y = f2bf(v.y); o.z = f2bf(v.z); o.w = f2bf(v.w);
        ((ushort4*)Xb)[i] = o;
        return;
    }
    i -= S2;
    if (i < S3) {   // Wcp[kq][n][j] = Wcat[kq*8+j][n], BN = 128
        int j = i & 7, rest = i >> 3;
        int n = rest % D, kq = rest / D;
        int k = kq * 8 + j;
        float v = (k < KREL) ? W1[(size_t)k * D + n] : root1[(size_t)(k - KREL) * D + n];
        Wp1[i] = (short)f2bf(v);
        return;
    }
    i -= S3;
    if (i < S4) {   // BN = 96
        int j = i & 7, rest = i >> 3;
        int n = rest % DOUT2, kq = rest / DOUT2;
        int k = kq * 8 + j;
        float v = (k < KREL) ? W2[(size_t)k * DOUT2 + n] : root2[(size_t)(k - KREL) * DOUT2 + n];
        Wp2[i] = (short)f2bf(v);
        return;
    }
}

// ---------------------------------------------------------------------------
// cnt[v][r] = #edges with dst=v, etype=r
__global__ void count_deg(const int* __restrict__ dst,
                          const int* __restrict__ et,
                          float* __restrict__ cnt) {
    int e = blockIdx.x * blockDim.x + threadIdx.x;
    if (e < NE) unsafeAtomicAdd(&cnt[dst[e] * NREL + et[e]], 1.0f);
}

// ---------------------------------------------------------------------------
// Prefix sum of per-node degree -> off[0..NN] (3-kernel scan)
__global__ void scan1(const float* __restrict__ cnt, int* __restrict__ bsum) {
    __shared__ int s[256];
    int tid = threadIdx.x;
    int base = blockIdx.x * 1024 + tid * 4;
    int t = 0;
    for (int i = 0; i < 4; i++) {
        int v = base + i;
        if (v < NN) {
            float4 c = *(const float4*)&cnt[(size_t)v * 4];
            t += (int)(c.x + c.y + c.z + c.w);
        }
    }
    s[tid] = t; __syncthreads();
    for (int o = 128; o > 0; o >>= 1) {
        if (tid < o) s[tid] += s[tid + o];
        __syncthreads();
    }
    if (tid == 0) bsum[blockIdx.x] = s[0];
}

__global__ void scan2(int* __restrict__ bsum) {  // 1 block of 128; exclusive in-place
    __shared__ int s[128];
    int tid = threadIdx.x;
    int mine = (tid < SCAN_B) ? bsum[tid] : 0;
    s[tid] = mine; __syncthreads();
    for (int o = 1; o < 128; o <<= 1) {
        int v = (tid >= o) ? s[tid - o] : 0;
        __syncthreads();
        s[tid] += v;
        __syncthreads();
    }
    if (tid < SCAN_B) bsum[tid] = s[tid] - mine;
}

__global__ void scan3(const float* __restrict__ cnt, const int* __restrict__ bsum,
                      int* __restrict__ off) {
    __shared__ int s[256];
    int tid = threadIdx.x;
    int base = blockIdx.x * 1024 + tid * 4;
    int d[4]; int t = 0;
    for (int i = 0; i < 4; i++) {
        int v = base + i; d[i] = 0;
        if (v < NN) {
            float4 c = *(const float4*)&cnt[(size_t)v * 4];
            d[i] = (int)(c.x + c.y + c.z + c.w);
        }
        t += d[i];
    }
    int mine = t;
    s[tid] = t; __syncthreads();
    for (int o = 1; o < 256; o <<= 1) {
        int v = (tid >= o) ? s[tid - o] : 0;
        __syncthreads();
        s[tid] += v;
        __syncthreads();
    }
    int ex = s[tid] - mine + bsum[blockIdx.x];
    for (int i = 0; i < 4; i++) {
        int v = base + i;
        if (v < NN) { off[v] = ex; ex += d[i]; }
    }
    if (blockIdx.x == 0 && tid == 0) off[NN] = NE;
}

// ---------------------------------------------------------------------------
// Bucket edges by dst; packed (src<<2)|etype
__global__ void bucket_edges(const int* __restrict__ src, const int* __restrict__ dst,
                             const int* __restrict__ et, const int* __restrict__ off,
                             int* __restrict__ fill, int* __restrict__ srcpk) {
    int e = blockIdx.x * blockDim.x + threadIdx.x;
    if (e >= NE) return;
    int dn = dst[e];
    int pos = off[dn] + atomicAdd(&fill[dn], 1);
    srcpk[pos] = (src[e] << 2) | et[e];
}

// ---------------------------------------------------------------------------
// Fused RGCN layer — R12 frame + clamped tail + off/cnt LDS staging (R13).
// Block = 256 threads (4 waves), 32 dst nodes; LDS: 32 KB A-tile + 4 KB idx
// + 33 off + 128 cnt floats (~37.5 KB, 4 blocks/CU).
// CAUSAL MODEL (R12 verified +7%): bound by serial memory round trips per
// chain; each removed dependent RT is a direct win. R13 removes two more:
//   (a) clamped 3-slot tail — 1..3 leftover edges = ONE gather trip instead
//       of 1..3 serial trips (zero-gated via t_=4, no divergence; tail regs
//       are live only after the 4-wide loop -> no spill risk);
//   (b) off[] / cnt[] staged into LDS in the coop prologue — the per-node
//       chain-HEAD loads become broadcast ds_reads, removing a ~200cy
//       global RT from the front of every node's dependence chain.
// Spill tripwire: WRITE_SIZE must stay == output (25000 KiB L1); VGPR 64-72.
//   Phase 1 4-wide body, XOR-swizzled staging (0 conflicts), root-MFMA
//   hoist, phase-2 quadrant split: identical to R12 (75.5 us measured).
template <int BN, bool RELU, bool OUT_BF16>
__global__ __launch_bounds__(256, 4) void rgcn_fused(
    const ushort* __restrict__ Xb,   // [M,128] bf16
    const int*   __restrict__ srcpk, // [NE] bucketed, (src<<2)|t
    const int*   __restrict__ off,   // [M+1]
    const float* __restrict__ cnt,   // [M,4]
    const short* __restrict__ Wcp,   // [80][BN][8] bf16
    const float* __restrict__ bias,  // [BN]
    void*        __restrict__ Cout,  // [M,BN] bf16 or f32
    int M) {
    constexpr int NFW = (BN / 16 + 1) / 2;   // frags per wave: 4 (BN=128) / 3 (BN=96)
    __shared__ short At[64 * 32 * 8];        // 32 KB
    __shared__ int   eidx[EMAX];             // 4 KB staged (src<<2)|t
    __shared__ int   soff[33];               // staged off[v0..v0+32]
    __shared__ float scnt[32 * 4];           // staged cnt rows

    const int tid  = threadIdx.x;
    const int wave = tid >> 6;
    const int lane = tid & 63;
    const int l    = lane & 15;     // phase1: feat group / phase2: m16
    const int qw   = lane >> 4;     // phase1: quarter / phase2: k-quad q
    const int g    = wave * 4 + qw; // chain id 0..15
    const int v0   = blockIdx.x * 32;

    // ---- cooperative prologue: stage off, cnt, and edge indices ----
    const int ebase = off[v0];
    const int nE    = off[v0 + 32] - ebase;
    const bool useL = (nE <= EMAX);
    if (tid < 33) soff[tid] = off[v0 + tid];
    if (tid >= 64 && tid < 96) {  // different wave than soff loaders: overlap
        int t2 = tid - 64;
        *(float4*)&scnt[t2 * 4] = *(const float4*)&cnt[(size_t)(v0 + t2) * 4];
    }
    if (useL) {
        for (int i = tid; i < nE; i += 256) eidx[i] = srcpk[ebase + i];
    }
    __syncthreads();

    // ---- phase 1: aggregate 32 nodes (2 per chain) ----
    // EDGE_ACC_G: gate==0 forces t_=4 -> all selects false -> zero contribution
#define EDGE_ACC_G(PK, XB, GOK) {                                           \
        int t_ = (GOK) ? ((PK) & 3) : 4;                                    \
        float s0 = (t_ == 0) ? nrm0 : 0.0f;                                 \
        float s1 = (t_ == 1) ? nrm1 : 0.0f;                                 \
        float s2 = (t_ == 2) ? nrm2 : 0.0f;                                 \
        float s3 = (t_ == 3) ? nrm3 : 0.0f;                                 \
        float xf[8];                                                        \
        xf[0] = bflo(XB.x); xf[1] = bfhi(XB.x);                             \
        xf[2] = bflo(XB.y); xf[3] = bfhi(XB.y);                             \
        xf[4] = bflo(XB.z); xf[5] = bfhi(XB.z);                             \
        xf[6] = bflo(XB.w); xf[7] = bfhi(XB.w);                             \
        _Pragma("unroll")                                                   \
        for (int j = 0; j < 8; j++) {                                       \
            acc[0][j] += s0 * xf[j];                                        \
            acc[1][j] += s1 * xf[j];                                        \
            acc[2][j] += s2 * xf[j];                                        \
            acc[3][j] += s3 * xf[j];                                        \
        } }
#define EDGE_ACC(PK, XB) EDGE_ACC_G(PK, XB, 1)

#define PHASE1_BODY(LOADI)                                                  \
    _Pragma("unroll")                                                       \
    for (int half = 0; half < 2; half++) {                                  \
        int nv = g + half * 16;                                             \
        int v  = v0 + nv;                                                   \
        (void)v;                                                            \
        float acc[4][8];                                                    \
        _Pragma("unroll")                                                   \
        for (int r = 0; r < 4; r++)                                         \
            _Pragma("unroll")                                               \
            for (int j = 0; j < 8; j++) acc[r][j] = 0.0f;                   \
        float4 c4 = *(const float4*)&scnt[nv * 4];                          \
        float nrm0 = 1.0f / fmaxf(c4.x, 1.0f);                              \
        float nrm1 = 1.0f / fmaxf(c4.y, 1.0f);                              \
        float nrm2 = 1.0f / fmaxf(c4.z, 1.0f);                              \
        float nrm3 = 1.0f / fmaxf(c4.w, 1.0f);                              \
        int e = soff[nv], end = soff[nv + 1];                               \
        for (; e + 3 < end; e += 4) {                                       \
            int p0 = LOADI(e),     p1 = LOADI(e + 1);                       \
            int p2 = LOADI(e + 2), p3 = LOADI(e + 3);                       \
            uint4 x0 = *(const uint4*)&Xb[(size_t)(p0 >> 2) * D + l * 8];   \
            uint4 x1 = *(const uint4*)&Xb[(size_t)(p1 >> 2) * D + l * 8];   \
            uint4 x2 = *(const uint4*)&Xb[(size_t)(p2 >> 2) * D + l * 8];   \
            uint4 x3 = *(const uint4*)&Xb[(size_t)(p3 >> 2) * D + l * 8];   \
            EDGE_ACC(p0, x0); EDGE_ACC(p1, x1);                             \
            EDGE_ACC(p2, x2); EDGE_ACC(p3, x3);                             \
        }                                                                   \
        if (e < end) {   /* clamped tail: 1..3 edges, ONE gather trip */    \
            int rem = end - e;                                              \
            int ea = e + ((rem > 1) ? 1 : 0);                               \
            int eb = e + ((rem > 2) ? 2 : 0);                               \
            int p0 = LOADI(e), p1 = LOADI(ea), p2 = LOADI(eb);              \
            uint4 x0 = *(const uint4*)&Xb[(size_t)(p0 >> 2) * D + l * 8];   \
            uint4 x1 = *(const uint4*)&Xb[(size_t)(p1 >> 2) * D + l * 8];   \
            uint4 x2 = *(const uint4*)&Xb[(size_t)(p2 >> 2) * D + l * 8];   \
            EDGE_ACC(p0, x0);                                               \
            EDGE_ACC_G(p1, x1, rem > 1);                                    \
            EDGE_ACC_G(p2, x2, rem > 2);                                    \
        }                                                                   \
        _Pragma("unroll")                                                   \
        for (int r = 0; r < 4; r++) {                                       \
            short8 w;                                                       \
            _Pragma("unroll")                                               \
            for (int j = 0; j < 8; j++) w[j] = (short)f2bf(acc[r][j]);      \
            int kq = r * 16 + l;                                            \
            *(short8*)&At[(kq * 32 + (nv ^ (kq & 7))) * 8] = w;             \
        }                                                                   \
    }

#define LOADI_LDS(E)  eidx[(E) - ebase]
#define LOADI_GLB(E)  srcpk[(E)]
    if (useL) { PHASE1_BODY(LOADI_LDS) }
    else      { PHASE1_BODY(LOADI_GLB) }
#undef LOADI_LDS
#undef LOADI_GLB
#undef PHASE1_BODY
#undef EDGE_ACC
#undef EDGE_ACC_G

    // ---- phase 2 setup ----
    const int m16   = l;
    const int q     = qw;
    const int mt    = wave & 1;           // m-half (16 nodes)
    const int nbase = (wave >> 1) * NFW * 16;   // n-offset
    f32x4 acc2[NFW];
#pragma unroll
    for (int i = 0; i < NFW; i++) acc2[i] = (f32x4)0.0f;

    // root part first (k = 512..639, global-only operands): phase-1 registers
    // are dead here; fast waves do these MFMAs while slow chains gather.
    {
        int rowc = v0 + mt * 16 + m16;
        const ushort* Xrow = Xb + (size_t)rowc * D;
#pragma unroll
        for (int s2 = 0; s2 < 4; s2++) {
            short8 af = *(const short8*)&Xrow[s2 * 32 + q * 8];
            const short* bbase = Wcp + ((size_t)((16 + s2) * 4 + q) * BN + nbase + m16) * 8;
#pragma unroll
            for (int nf = 0; nf < NFW; nf++) {
                short8 bf = *(const short8*)(bbase + nf * 128);
                acc2[nf] = __builtin_amdgcn_mfma_f32_16x16x32_bf16(af, bf, acc2[nf], 0, 0, 0);
            }
        }
    }

    __syncthreads();

    // ---- phase 2: 32x512 @ 512xBN from LDS, one quadrant per wave ----
#pragma unroll 4
    for (int ks = 0; ks < 16; ks++) {
        int kq = ks * 4 + q;
        short8 af = *(const short8*)&At[(kq * 32 + ((mt * 16 + m16) ^ (kq & 7))) * 8];
        const short* bbase = Wcp + ((size_t)kq * BN + nbase + m16) * 8;
#pragma unroll
        for (int nf = 0; nf < NFW; nf++) {
            short8 bf = *(const short8*)(bbase + nf * 128);
            acc2[nf] = __builtin_amdgcn_mfma_f32_16x16x32_bf16(af, bf, acc2[nf], 0, 0, 0);
        }
    }

    // ---- epilogue ----
#pragma unroll
    for (int nf = 0; nf < NFW; nf++) {
        int n = nbase + nf * 16 + m16;
        float b = bias[n];
#pragma unroll
        for (int r = 0; r < 4; r++) {
            int m = v0 + mt * 16 + q * 4 + r;
            float vv = acc2[nf][r] + b;
            if (RELU) vv = fmaxf(vv, 0.0f);
            if (OUT_BF16) ((ushort*)Cout)[(size_t)m * BN + n] = f2bf(vv);
            else          ((float*)Cout)[(size_t)m * BN + n]  = vv;
        }
    }
}

// ---------------------------------------------------------------------------
extern "C" void kernel_launch(void* const* d_in, const int* in_sizes, int n_in,
                              void* d_out, int out_size, void* d_ws, size_t ws_size,
                              hipStream_t stream) {
    const float* x     = (const float*)d_in[0];
    const int*   ei    = (const int*)d_in[1];
    const int*   et    = (const int*)d_in[2];
    const float* W1    = (const float*)d_in[3];
    const float* root1 = (const float*)d_in[4];
    const float* b1    = (const float*)d_in[5];
    const float* W2    = (const float*)d_in[6];
    const float* root2 = (const float*)d_in[7];
    const float* b2    = (const float*)d_in[8];
    const int* srcp = ei;
    const int* dstp = ei + NE;
    float* out = (float*)d_out;

    // Workspace layout (all segments 16-B aligned)
    short*  Wp1  = (short*)d_ws;                          // 640*128 bf16
    short*  Wp2  = Wp1 + (size_t)KCAT * D;                // 640*96  bf16
    ushort* Xb   = (ushort*)(Wp2 + (size_t)KCAT * DOUT2); // NN*128 bf16
    ushort* h    = Xb + (size_t)NN * D;                   // NN*128 bf16
    float*  cnt  = (float*)(h + (size_t)NN * D);          // NN*4 f32
    int*    off  = (int*)(cnt + (size_t)NN * NREL);       // NN+1
    int*    fill = off + (NN + 1);                        // NN
    int*    bsum = fill + NN;                             // 128
    int*    srcpk= bsum + 128;                            // NE

    // ---- prep (shared by both layers) ----
    {
        const int S = (NN * NREL) / 4 + NN / 4 + (NN * D) / 4 + KCAT * D + KCAT * DOUT2;
        prep0<<<(S + 255) / 256, 256, 0, stream>>>(x, Xb, W1, root1, Wp1,
                                                   W2, root2, Wp2, cnt, fill);
    }
    count_deg<<<(NE + 255) / 256, 256, 0, stream>>>(dstp, et, cnt);
    scan1<<<SCAN_B, 256, 0, stream>>>(cnt, bsum);
    scan2<<<1, 128, 0, stream>>>(bsum);
    scan3<<<SCAN_B, 256, 0, stream>>>(cnt, bsum, off);
    bucket_edges<<<(NE + 255) / 256, 256, 0, stream>>>(srcp, dstp, et, off, fill, srcpk);

    const int fblocks = NN / 32;  // 3125 (exact)

    // ---- Layer 1: h = relu(agg(x) @ W1cat + b1), bf16 out ----
    rgcn_fused<128, true, true><<<fblocks, 256, 0, stream>>>(
        Xb, srcpk, off, cnt, Wp1, b1, h, NN);
    // ---- Layer 2: out = agg(h) @ W2cat + b2, f32 out ----
    rgcn_fused<96, false, false><<<fblocks, 256, 0, stream>>>(
        h, srcpk, off, cnt, Wp2, b2, out, NN);
}